// Round 8
// baseline (296.778 us; speedup 1.0000x reference)
//
#include <hip/hip_runtime.h>

// GNN: 2x GCNConv(relu) + mean-pool + MLP head. All f32.
// Sizes fixed by problem: N=50000, E=800000, F_IN=256, H=64, NG=64, NC=4.
//
// Pipeline: passA bucket staging -> passB (inline bucket scan) -> gemm1 ->
// agg1 -> gemm2 -> agg2+pool fused -> gcnt -> head1 -> head2.
// R7: top-5 masked by harness 0xAA fill (42us) — per-kernel counters blind.

#define TPB 256
#define CHUNK_A 4096
#define BCAP 4608          // per-bucket staging capacity (mean 4096, +8 sigma)

// ---------------- pass A: chunked bucket staging ----------------
// packed edge: (src<<8) | (dst & 255); requires n <= 65536, nbuck <= 256.

__global__ __launch_bounds__(TPB) void k_passA(const int* __restrict__ srcv,
                                               const int* __restrict__ dstv, int E,
                                               int* __restrict__ gcur,
                                               int* __restrict__ staged, int nbuck) {
    __shared__ int pk[CHUNK_A];
    __shared__ int hist[256];
    __shared__ int ebase[256];
    __shared__ int gbase[256];
    __shared__ int lcur[256];
    int t = threadIdx.x;
    int e0 = blockIdx.x * CHUNK_A;
    int e1 = e0 + CHUNK_A; if (e1 > E) e1 = E;

    hist[t] = 0; lcur[t] = 0;
    __syncthreads();
    for (int i = e0 + t; i < e1; i += TPB) atomicAdd(&hist[dstv[i] >> 8], 1);
    __syncthreads();
    int v = hist[t];
    ebase[t] = v;
    __syncthreads();
    for (int off = 1; off < 256; off <<= 1) {
        int u = (t >= off) ? ebase[t - off] : 0;
        __syncthreads();
        ebase[t] += u;
        __syncthreads();
    }
    ebase[t] -= v;
    if (t < nbuck && v > 0) gbase[t] = t * BCAP + atomicAdd(&gcur[t], v);
    __syncthreads();
    for (int i = e0 + t; i < e1; i += TPB) {
        int d = dstv[i];
        int s = srcv[i];
        int b = d >> 8;
        int r = atomicAdd(&lcur[b], 1);
        pk[ebase[b] + r] = (s << 8) | (d & 255);
    }
    __syncthreads();
    int wave = t >> 6, lane = t & 63;
    for (int b = wave; b < nbuck; b += 4) {
        int c = hist[b];
        int lb = ebase[b];
        int gb = gbase[b];
        for (int j = lane; j < c; j += 64) staged[gb + j] = pk[lb + j];
    }
}

// ---------------- pass B: per-bucket node sort + csr_off + dinv ----------------
// bucket_off computed inline (196-entry scan of gcur, redundant per block).

__global__ __launch_bounds__(TPB) void k_passB(const int* __restrict__ staged,
                                               const int* __restrict__ gcur,
                                               int* __restrict__ csr_off,
                                               int* __restrict__ csr_src,
                                               float* __restrict__ dinv,
                                               int n, int nbuck) {
    __shared__ int pk[BCAP];
    __shared__ int soff[256];
    __shared__ int hist[256];
    __shared__ int nbase[256];
    __shared__ int cur[256];
    int b = blockIdx.x;
    int n0 = b << 8;
    int n1 = n0 + 256; if (n1 > n) n1 = n;
    int cnt = gcur[b];
    int t = threadIdx.x;

    // inline exclusive bucket-offset: scan gcur[0..nbuck)
    int cv = (t < nbuck) ? gcur[t] : 0;
    soff[t] = cv;
    hist[t] = 0; cur[t] = 0;
    __syncthreads();
    for (int off = 1; off < 256; off <<= 1) {
        int u = (t >= off) ? soff[t - off] : 0;
        __syncthreads();
        soff[t] += u;
        __syncthreads();
    }
    int base = soff[b] - cnt;   // exclusive prefix at index b

    for (int i = t; i < cnt; i += TPB) pk[i] = staged[b * BCAP + i];
    __syncthreads();
    for (int i = t; i < cnt; i += TPB) atomicAdd(&hist[pk[i] & 255], 1);
    __syncthreads();
    int v = hist[t];
    nbase[t] = v;
    __syncthreads();
    for (int off = 1; off < 256; off <<= 1) {
        int u = (t >= off) ? nbase[t - off] : 0;
        __syncthreads();
        nbase[t] += u;
        __syncthreads();
    }
    nbase[t] -= v;
    if (n0 + t < n1) {
        csr_off[n0 + t] = base + nbase[t];
        dinv[n0 + t] = rsqrtf((float)(v + 1));   // +1 self loop
    }
    if (b == nbuck - 1 && t == 0) csr_off[n] = base + cnt;
    __syncthreads();
    for (int i = t; i < cnt; i += TPB) {
        int p = pk[i];
        int dloc = p & 255;
        int r = atomicAdd(&cur[dloc], 1);
        csr_src[base + nbase[dloc] + r] = p >> 8;
    }
}

// ---------------- GEMM: C[r][j] = dinv[r] * sum_k A[r][k] * W[k][j], j in [0,64) ----------------
// xr stored [kk][row] so the inner loop is 2x ds_read_b128 per kk.

template <int K>
__global__ __launch_bounds__(TPB) void k_gemm_scaled(const float* __restrict__ A,
                                                     const float* __restrict__ W,
                                                     const float* __restrict__ dinv,
                                                     float* __restrict__ C, int n) {
    __shared__ __align__(16) float Wc[64 * 64];    // [kk][j]
    __shared__ __align__(16) float xr[64 * 68];    // [kk][row], stride 68
    const int t = threadIdx.x;
    const int wave = t >> 6, lane = t & 63;
    const int li = lane >> 4, lj = lane & 15;
    const int rl0 = wave * 16 + li * 4;
    const int rbase = blockIdx.x * 64;

    float acc[4][4] = {{0.f,0.f,0.f,0.f},{0.f,0.f,0.f,0.f},{0.f,0.f,0.f,0.f},{0.f,0.f,0.f,0.f}};

    for (int kc = 0; kc < K; kc += 64) {
        {
            const float4* wsv = (const float4*)(W + (size_t)kc * 64);
            float4* wd = (float4*)Wc;
#pragma unroll
            for (int q = 0; q < 4; q++) wd[t + q * 256] = wsv[t + q * 256];
        }
        {
            int rl = t >> 2;
            int kq = (t & 3) * 16;
            int r = rbase + rl;
#pragma unroll
            for (int m = 0; m < 16; m += 4) {
                float4 xv;
                if (r < n) xv = *(const float4*)&A[(size_t)r * K + kc + kq + m];
                else       xv = make_float4(0.f, 0.f, 0.f, 0.f);
                xr[(kq + m + 0) * 68 + rl] = xv.x;
                xr[(kq + m + 1) * 68 + rl] = xv.y;
                xr[(kq + m + 2) * 68 + rl] = xv.z;
                xr[(kq + m + 3) * 68 + rl] = xv.w;
            }
        }
        __syncthreads();
#pragma unroll 8
        for (int kk = 0; kk < 64; kk++) {
            float4 wv = *(const float4*)&Wc[kk * 64 + lj * 4];
            float4 xv = *(const float4*)&xr[kk * 68 + rl0];
            acc[0][0] += xv.x * wv.x; acc[0][1] += xv.x * wv.y; acc[0][2] += xv.x * wv.z; acc[0][3] += xv.x * wv.w;
            acc[1][0] += xv.y * wv.x; acc[1][1] += xv.y * wv.y; acc[1][2] += xv.y * wv.z; acc[1][3] += xv.y * wv.w;
            acc[2][0] += xv.z * wv.x; acc[2][1] += xv.z * wv.y; acc[2][2] += xv.z * wv.z; acc[2][3] += xv.z * wv.w;
            acc[3][0] += xv.w * wv.x; acc[3][1] += xv.w * wv.y; acc[3][2] += xv.w * wv.z; acc[3][3] += xv.w * wv.w;
        }
        __syncthreads();
    }

#pragma unroll
    for (int ri = 0; ri < 4; ri++) {
        int r = rbase + rl0 + ri;
        if (r < n) {
            float d = dinv[r];
            float4 o = make_float4(acc[ri][0] * d, acc[ri][1] * d, acc[ri][2] * d, acc[ri][3] * d);
            *(float4*)&C[(size_t)r * 64 + lj * 4] = o;
        }
    }
}

// ---------------- Aggregation layer 1 (CSR gather), writes out ----------------

__global__ __launch_bounds__(TPB) void k_agg(const float* __restrict__ hs,
                                             const int* __restrict__ csr_off,
                                             const int* __restrict__ csr_src,
                                             const float* __restrict__ dinv,
                                             const float* __restrict__ bias,
                                             float* __restrict__ out, int n) {
    int node = blockIdx.x * 4 + (threadIdx.x >> 6);
    int lane = threadIdx.x & 63;
    if (node >= n) return;
    int p0 = csr_off[node];
    int p1 = csr_off[node + 1];
    float acc = hs[(size_t)node * 64 + lane];  // self loop
    int p = p0;
    for (; p + 8 <= p1; p += 8) {
        int s0 = csr_src[p + 0];
        int s1 = csr_src[p + 1];
        int s2 = csr_src[p + 2];
        int s3 = csr_src[p + 3];
        int s4 = csr_src[p + 4];
        int s5 = csr_src[p + 5];
        int s6 = csr_src[p + 6];
        int s7 = csr_src[p + 7];
        float a0 = hs[(size_t)s0 * 64 + lane];
        float a1 = hs[(size_t)s1 * 64 + lane];
        float a2 = hs[(size_t)s2 * 64 + lane];
        float a3 = hs[(size_t)s3 * 64 + lane];
        float a4 = hs[(size_t)s4 * 64 + lane];
        float a5 = hs[(size_t)s5 * 64 + lane];
        float a6 = hs[(size_t)s6 * 64 + lane];
        float a7 = hs[(size_t)s7 * 64 + lane];
        acc += ((a0 + a1) + (a2 + a3)) + ((a4 + a5) + (a6 + a7));
    }
    for (; p < p1; p++) acc += hs[(size_t)csr_src[p] * 64 + lane];
    float v = dinv[node] * acc + bias[lane];
    out[(size_t)node * 64 + lane] = fmaxf(v, 0.f);
}

// ---------------- Aggregation layer 2 fused with mean-pool sum ----------------
// No hb write: relu'd row goes straight into gsum (batch sorted -> block's 4
// nodes usually one group -> LDS reduce, 1 atomic/lane/block).

__global__ __launch_bounds__(TPB) void k_aggp(const float* __restrict__ hs,
                                              const int* __restrict__ csr_off,
                                              const int* __restrict__ csr_src,
                                              const float* __restrict__ dinv,
                                              const float* __restrict__ bias,
                                              const int* __restrict__ batch,
                                              float* __restrict__ gsum, int n) {
    __shared__ float red[4][64];
    __shared__ int grp[4];
    __shared__ int uni;
    int w = threadIdx.x >> 6;
    int lane = threadIdx.x & 63;
    int node = blockIdx.x * 4 + w;
    bool valid = node < n;

    float v = 0.f;
    int g = -1;
    if (valid) {
        int p0 = csr_off[node];
        int p1 = csr_off[node + 1];
        float acc = hs[(size_t)node * 64 + lane];
        int p = p0;
        for (; p + 8 <= p1; p += 8) {
            int s0 = csr_src[p + 0];
            int s1 = csr_src[p + 1];
            int s2 = csr_src[p + 2];
            int s3 = csr_src[p + 3];
            int s4 = csr_src[p + 4];
            int s5 = csr_src[p + 5];
            int s6 = csr_src[p + 6];
            int s7 = csr_src[p + 7];
            float a0 = hs[(size_t)s0 * 64 + lane];
            float a1 = hs[(size_t)s1 * 64 + lane];
            float a2 = hs[(size_t)s2 * 64 + lane];
            float a3 = hs[(size_t)s3 * 64 + lane];
            float a4 = hs[(size_t)s4 * 64 + lane];
            float a5 = hs[(size_t)s5 * 64 + lane];
            float a6 = hs[(size_t)s6 * 64 + lane];
            float a7 = hs[(size_t)s7 * 64 + lane];
            acc += ((a0 + a1) + (a2 + a3)) + ((a4 + a5) + (a6 + a7));
        }
        for (; p < p1; p++) acc += hs[(size_t)csr_src[p] * 64 + lane];
        v = fmaxf(dinv[node] * acc + bias[lane], 0.f);
        g = batch[node];
    }
    red[w][lane] = v;
    if (lane == 0) grp[w] = g;
    __syncthreads();
    if (threadIdx.x == 0)
        uni = (grp[0] >= 0) && (grp[1] == grp[0]) && (grp[2] == grp[0]) && (grp[3] == grp[0]);
    __syncthreads();
    if (uni) {
        if (w == 0) {
            float s = (red[0][lane] + red[1][lane]) + (red[2][lane] + red[3][lane]);
            atomicAdd(&gsum[grp[0] * 64 + lane], s);
        }
    } else if (valid) {
        atomicAdd(&gsum[g * 64 + lane], v);
    }
}

// ---------------- group counts (wave-dedup'd atomics) ----------------

__global__ __launch_bounds__(TPB) void k_gcnt(const int* __restrict__ batch, int n,
                                              int* __restrict__ gcnt) {
    int i = blockIdx.x * TPB + threadIdx.x;
    int lane = threadIdx.x & 63;
    int g = (i < n) ? batch[i] : -1;
    int g0 = __shfl(g, 0);
    unsigned long long bm = __ballot(g == g0 && g >= 0);
    if (bm == ~0ull) {
        if (lane == 0) atomicAdd(&gcnt[g0], 64);
    } else if (g >= 0) {
        atomicAdd(&gcnt[g], 1);
    }
}

// ---------------- Head, stage 1 ----------------

__global__ __launch_bounds__(TPB) void k_head1(const float* __restrict__ gsum,
                                               const int* __restrict__ gcnt,
                                               const float* __restrict__ fc1w,
                                               const float* __restrict__ fc1b,
                                               float* __restrict__ z) {
    int t = threadIdx.x;
    int g = blockIdx.x * 2 + (t >> 7);
    int o = t & 127;
    int c = gcnt[g]; if (c < 1) c = 1;
    float inv = 1.0f / (float)c;
    float a = fc1b[o];
#pragma unroll 16
    for (int j = 0; j < 64; j++) {
        float pj = gsum[g * 64 + j] * inv;
        a += pj * fc1w[j * 128 + o];
    }
    z[g * 128 + o] = fmaxf(a, 0.f);
}

// ---------------- Head, stage 2 ----------------

__global__ __launch_bounds__(TPB) void k_head2(const float* __restrict__ z,
                                               const float* __restrict__ fc2w,
                                               const float* __restrict__ fc2b,
                                               float* __restrict__ out) {
    int t = threadIdx.x;
    int g = t >> 2, c = t & 3;
    float a = fc2b[c];
#pragma unroll 16
    for (int o = 0; o < 128; o++) a += z[g * 128 + o] * fc2w[o * 4 + c];
    out[t] = a;
}

// ---------------- launch ----------------

extern "C" void kernel_launch(void* const* d_in, const int* in_sizes, int n_in,
                              void* d_out, int out_size, void* d_ws, size_t ws_size,
                              hipStream_t stream) {
    const float* x    = (const float*)d_in[0];
    const int*   ei   = (const int*)d_in[1];
    const int*   batch= (const int*)d_in[2];
    const float* W1   = (const float*)d_in[3];
    const float* b1   = (const float*)d_in[4];
    const float* W2   = (const float*)d_in[5];
    const float* b2   = (const float*)d_in[6];
    const float* fc1w = (const float*)d_in[7];
    const float* fc1b = (const float*)d_in[8];
    const float* fc2w = (const float*)d_in[9];
    const float* fc2b = (const float*)d_in[10];

    const int n = in_sizes[2];        // 50000
    const int E = in_sizes[1] / 2;    // 800000
    const int* srcv = ei;
    const int* dstv = ei + E;
    const int nbuck = (n + 255) >> 8; // 196 (must be <= 256)

    // workspace carve; zeroed region contiguous at front
    char* w = (char*)d_ws;
    int*   gcur   = (int*)w;            w += 256 * 4;
    int*   gcnt   = (int*)w;            w += 64 * 4;
    float* gsum   = (float*)w;          w += 64 * 64 * 4;
    size_t zbytes = (size_t)w - (size_t)d_ws;
    int*   csr_off= (int*)w;            w += (size_t)(n + 1) * 4;
    float* dinv   = (float*)w;          w += (size_t)n * 4;
    int*   csr_src= (int*)w;            w += (size_t)E * 4;
    int*   staged = (int*)w;            w += (size_t)nbuck * BCAP * 4;
    float* zbuf   = (float*)w;          w += 64 * 128 * 4;
    w = (char*)(((size_t)w + 255) & ~(size_t)255);
    float* hs = (float*)w;              w += (size_t)n * 64 * 4;
    float* hb = (float*)w;              w += (size_t)n * 64 * 4;

    hipMemsetAsync(d_ws, 0, zbytes, stream);

    int gA = (E + CHUNK_A - 1) / CHUNK_A;   // 196
    k_passA<<<gA, TPB, 0, stream>>>(srcv, dstv, E, gcur, staged, nbuck);
    k_passB<<<nbuck, TPB, 0, stream>>>(staged, gcur, csr_off, csr_src, dinv, n, nbuck);

    int gRows = (n + 63) / 64;
    int gNode = (n + 3) / 4;
    k_gemm_scaled<256><<<gRows, TPB, 0, stream>>>(x, W1, dinv, hs, n);
    k_agg<<<gNode, TPB, 0, stream>>>(hs, csr_off, csr_src, dinv, b1, hb, n);
    k_gemm_scaled<64><<<gRows, TPB, 0, stream>>>(hb, W2, dinv, hs, n);
    k_aggp<<<gNode, TPB, 0, stream>>>(hs, csr_off, csr_src, dinv, b2, batch, gsum, n);

    k_gcnt<<<(n + TPB - 1) / TPB, TPB, 0, stream>>>(batch, n, gcnt);
    k_head1<<<32, TPB, 0, stream>>>(gsum, gcnt, fc1w, fc1b, zbuf);
    k_head2<<<1, TPB, 0, stream>>>(zbuf, fc2w, fc2b, (float*)d_out);
}

// Round 9
// 271.050 us; speedup vs baseline: 1.0949x; 1.0949x over previous
//
#include <hip/hip_runtime.h>

// GNN: 2x GCNConv(relu) + mean-pool + MLP head.
// Sizes fixed: N=50000, E=800000, F_IN=256, H=64, NG=64, NC=4.
//
// R9: intermediates hs/hb stored bf16 (gathers are fetch-bound: R8 counters
// showed 81MB @1.6TB/s per agg). Accumulation f32. R8's aggp fusion and gemm
// xr-transpose reverted (both regressed; agg is fetch-bound, fusion extended
// its critical path).

#define TPB 256
#define CHUNK_A 4096
#define BCAP 4608          // per-bucket staging capacity (mean 4096, +8 sigma)

typedef unsigned short bfu;

__device__ __forceinline__ float bf2f(bfu u) {
    union { unsigned u32; float f; } c; c.u32 = ((unsigned)u) << 16; return c.f;
}
__device__ __forceinline__ bfu f2bf(float f) {
    union { float f; unsigned u; } c; c.f = f;
    unsigned r = 0x7FFFu + ((c.u >> 16) & 1u);     // round-to-nearest-even
    return (bfu)((c.u + r) >> 16);
}
__device__ __forceinline__ float blo(unsigned w) {
    union { unsigned u32; float f; } c; c.u32 = w << 16; return c.f;
}
__device__ __forceinline__ float bhi(unsigned w) {
    union { unsigned u32; float f; } c; c.u32 = w & 0xFFFF0000u; return c.f;
}

// ---------------- pass A: chunked bucket staging ----------------
// packed edge: (src<<8) | (dst & 255); requires n <= 65536, nbuck <= 256.

__global__ __launch_bounds__(TPB) void k_passA(const int* __restrict__ srcv,
                                               const int* __restrict__ dstv, int E,
                                               int* __restrict__ gcur,
                                               int* __restrict__ staged, int nbuck) {
    __shared__ int pk[CHUNK_A];
    __shared__ int hist[256];
    __shared__ int ebase[256];
    __shared__ int gbase[256];
    __shared__ int lcur[256];
    int t = threadIdx.x;
    int e0 = blockIdx.x * CHUNK_A;
    int e1 = e0 + CHUNK_A; if (e1 > E) e1 = E;

    hist[t] = 0; lcur[t] = 0;
    __syncthreads();
    for (int i = e0 + t; i < e1; i += TPB) atomicAdd(&hist[dstv[i] >> 8], 1);
    __syncthreads();
    int v = hist[t];
    ebase[t] = v;
    __syncthreads();
    for (int off = 1; off < 256; off <<= 1) {
        int u = (t >= off) ? ebase[t - off] : 0;
        __syncthreads();
        ebase[t] += u;
        __syncthreads();
    }
    ebase[t] -= v;
    if (t < nbuck && v > 0) gbase[t] = t * BCAP + atomicAdd(&gcur[t], v);
    __syncthreads();
    for (int i = e0 + t; i < e1; i += TPB) {
        int d = dstv[i];
        int s = srcv[i];
        int b = d >> 8;
        int r = atomicAdd(&lcur[b], 1);
        pk[ebase[b] + r] = (s << 8) | (d & 255);
    }
    __syncthreads();
    int wave = t >> 6, lane = t & 63;
    for (int b = wave; b < nbuck; b += 4) {
        int c = hist[b];
        int lb = ebase[b];
        int gb = gbase[b];
        for (int j = lane; j < c; j += 64) staged[gb + j] = pk[lb + j];
    }
}

// ---------------- pass B: per-bucket node sort + csr_off + dinv ----------------
// bucket offsets computed inline (nbuck-entry scan of gcur, redundant per block).

__global__ __launch_bounds__(TPB) void k_passB(const int* __restrict__ staged,
                                               const int* __restrict__ gcur,
                                               int* __restrict__ csr_off,
                                               int* __restrict__ csr_src,
                                               float* __restrict__ dinv,
                                               int n, int nbuck) {
    __shared__ int pk[BCAP];
    __shared__ int soff[256];
    __shared__ int hist[256];
    __shared__ int nbase[256];
    __shared__ int cur[256];
    int b = blockIdx.x;
    int n0 = b << 8;
    int n1 = n0 + 256; if (n1 > n) n1 = n;
    int cnt = gcur[b];
    int t = threadIdx.x;

    int cv = (t < nbuck) ? gcur[t] : 0;
    soff[t] = cv;
    hist[t] = 0; cur[t] = 0;
    __syncthreads();
    for (int off = 1; off < 256; off <<= 1) {
        int u = (t >= off) ? soff[t - off] : 0;
        __syncthreads();
        soff[t] += u;
        __syncthreads();
    }
    int base = soff[b] - cnt;   // exclusive prefix at bucket b

    for (int i = t; i < cnt; i += TPB) pk[i] = staged[b * BCAP + i];
    __syncthreads();
    for (int i = t; i < cnt; i += TPB) atomicAdd(&hist[pk[i] & 255], 1);
    __syncthreads();
    int v = hist[t];
    nbase[t] = v;
    __syncthreads();
    for (int off = 1; off < 256; off <<= 1) {
        int u = (t >= off) ? nbase[t - off] : 0;
        __syncthreads();
        nbase[t] += u;
        __syncthreads();
    }
    nbase[t] -= v;
    if (n0 + t < n1) {
        csr_off[n0 + t] = base + nbase[t];
        dinv[n0 + t] = rsqrtf((float)(v + 1));   // +1 self loop
    }
    if (b == nbuck - 1 && t == 0) csr_off[n] = base + cnt;
    __syncthreads();
    for (int i = t; i < cnt; i += TPB) {
        int p = pk[i];
        int dloc = p & 255;
        int r = atomicAdd(&cur[dloc], 1);
        csr_src[base + nbase[dloc] + r] = p >> 8;
    }
}

// ---------------- GEMM: C[r][j] = dinv[r] * sum_k A[r][k] * W[k][j] ----------------
// A is f32 (layer1: x) or bf16 (layer2: hb). C written bf16. xr [row][kk] (+68 pad).

template <int K, bool BF16A>
__global__ __launch_bounds__(TPB) void k_gemm(const void* __restrict__ Av,
                                              const float* __restrict__ W,
                                              const float* __restrict__ dinv,
                                              bfu* __restrict__ C, int n) {
    __shared__ __align__(16) float Wc[64 * 64];
    __shared__ __align__(16) float xr[64 * 68];
    const int t = threadIdx.x;
    const int wave = t >> 6, lane = t & 63;
    const int li = lane >> 4, lj = lane & 15;
    const int rl0 = wave * 16 + li * 4;
    const int rbase = blockIdx.x * 64;

    float acc[4][4] = {{0.f,0.f,0.f,0.f},{0.f,0.f,0.f,0.f},{0.f,0.f,0.f,0.f},{0.f,0.f,0.f,0.f}};

    for (int kc = 0; kc < K; kc += 64) {
        {
            const float4* wsv = (const float4*)(W + (size_t)kc * 64);
            float4* wd = (float4*)Wc;
#pragma unroll
            for (int q = 0; q < 4; q++) wd[t + q * 256] = wsv[t + q * 256];
        }
        {
            int rl = t >> 2;
            int kq = (t & 3) * 16;
            int r = rbase + rl;
            if (!BF16A) {
                const float* A = (const float*)Av;
#pragma unroll
                for (int m = 0; m < 16; m += 4) {
                    float4 xv;
                    if (r < n) xv = *(const float4*)&A[(size_t)r * K + kc + kq + m];
                    else       xv = make_float4(0.f, 0.f, 0.f, 0.f);
                    *(float4*)&xr[rl * 68 + kq + m] = xv;
                }
            } else {
                const bfu* A = (const bfu*)Av;
                uint4 p0 = make_uint4(0,0,0,0), p1 = make_uint4(0,0,0,0);
                if (r < n) {
                    const uint4* ap = (const uint4*)(A + (size_t)r * K + kc + kq);
                    p0 = ap[0]; p1 = ap[1];
                }
                *(float4*)&xr[rl * 68 + kq + 0]  = make_float4(blo(p0.x), bhi(p0.x), blo(p0.y), bhi(p0.y));
                *(float4*)&xr[rl * 68 + kq + 4]  = make_float4(blo(p0.z), bhi(p0.z), blo(p0.w), bhi(p0.w));
                *(float4*)&xr[rl * 68 + kq + 8]  = make_float4(blo(p1.x), bhi(p1.x), blo(p1.y), bhi(p1.y));
                *(float4*)&xr[rl * 68 + kq + 12] = make_float4(blo(p1.z), bhi(p1.z), blo(p1.w), bhi(p1.w));
            }
        }
        __syncthreads();
#pragma unroll 8
        for (int kk = 0; kk < 64; kk++) {
            float4 wv = *(const float4*)&Wc[kk * 64 + lj * 4];
            float x0 = xr[(rl0 + 0) * 68 + kk];
            float x1 = xr[(rl0 + 1) * 68 + kk];
            float x2 = xr[(rl0 + 2) * 68 + kk];
            float x3 = xr[(rl0 + 3) * 68 + kk];
            acc[0][0] += x0 * wv.x; acc[0][1] += x0 * wv.y; acc[0][2] += x0 * wv.z; acc[0][3] += x0 * wv.w;
            acc[1][0] += x1 * wv.x; acc[1][1] += x1 * wv.y; acc[1][2] += x1 * wv.z; acc[1][3] += x1 * wv.w;
            acc[2][0] += x2 * wv.x; acc[2][1] += x2 * wv.y; acc[2][2] += x2 * wv.z; acc[2][3] += x2 * wv.w;
            acc[3][0] += x3 * wv.x; acc[3][1] += x3 * wv.y; acc[3][2] += x3 * wv.z; acc[3][3] += x3 * wv.w;
        }
        __syncthreads();
    }

#pragma unroll
    for (int ri = 0; ri < 4; ri++) {
        int r = rbase + rl0 + ri;
        if (r < n) {
            float d = dinv[r];
            ushort4 o;
            o.x = f2bf(acc[ri][0] * d);
            o.y = f2bf(acc[ri][1] * d);
            o.z = f2bf(acc[ri][2] * d);
            o.w = f2bf(acc[ri][3] * d);
            *(ushort4*)&C[(size_t)r * 64 + lj * 4] = o;
        }
    }
}

// ---------------- Aggregation (CSR gather, bf16 rows, f32 accumulate) ----------------

__global__ __launch_bounds__(TPB) void k_agg(const bfu* __restrict__ hs,
                                             const int* __restrict__ csr_off,
                                             const int* __restrict__ csr_src,
                                             const float* __restrict__ dinv,
                                             const float* __restrict__ bias,
                                             bfu* __restrict__ out, int n) {
    int node = blockIdx.x * 4 + (threadIdx.x >> 6);
    int lane = threadIdx.x & 63;
    if (node >= n) return;
    int p0 = csr_off[node];
    int p1 = csr_off[node + 1];
    float acc = bf2f(hs[(size_t)node * 64 + lane]);  // self loop
    int p = p0;
    for (; p + 8 <= p1; p += 8) {
        int s0 = csr_src[p + 0];
        int s1 = csr_src[p + 1];
        int s2 = csr_src[p + 2];
        int s3 = csr_src[p + 3];
        int s4 = csr_src[p + 4];
        int s5 = csr_src[p + 5];
        int s6 = csr_src[p + 6];
        int s7 = csr_src[p + 7];
        float a0 = bf2f(hs[(size_t)s0 * 64 + lane]);
        float a1 = bf2f(hs[(size_t)s1 * 64 + lane]);
        float a2 = bf2f(hs[(size_t)s2 * 64 + lane]);
        float a3 = bf2f(hs[(size_t)s3 * 64 + lane]);
        float a4 = bf2f(hs[(size_t)s4 * 64 + lane]);
        float a5 = bf2f(hs[(size_t)s5 * 64 + lane]);
        float a6 = bf2f(hs[(size_t)s6 * 64 + lane]);
        float a7 = bf2f(hs[(size_t)s7 * 64 + lane]);
        acc += ((a0 + a1) + (a2 + a3)) + ((a4 + a5) + (a6 + a7));
    }
    for (; p < p1; p++) acc += bf2f(hs[(size_t)csr_src[p] * 64 + lane]);
    float v = dinv[node] * acc + bias[lane];
    out[(size_t)node * 64 + lane] = f2bf(fmaxf(v, 0.f));
}

// ---------------- Pool: sorted batch; uniform-chunk fast path (bf16 reads) ----------------

__global__ __launch_bounds__(TPB) void k_pool(const bfu* __restrict__ h,
                                              const int* __restrict__ batch, int n,
                                              float* __restrict__ gsum,
                                              int* __restrict__ gcnt) {
    const int CH = 16;
    int wid = blockIdx.x * 4 + (threadIdx.x >> 6);
    int lane = threadIdx.x & 63;
    int i0 = wid * CH;
    if (i0 >= n) return;
    int i1 = i0 + CH; if (i1 > n) i1 = n;
    int g0 = batch[i0];
    int g1 = batch[i1 - 1];
    if (g0 == g1) {
        float acc = 0.f;
#pragma unroll
        for (int i = 0; i < CH; i++) {
            int idx = i0 + i;
            if (idx < i1) acc += bf2f(h[(size_t)idx * 64 + lane]);
        }
        atomicAdd(&gsum[g0 * 64 + lane], acc);
        if (lane == 0) atomicAdd(&gcnt[g0], i1 - i0);
    } else {
        int cur = g0;
        float acc = 0.f;
        int cnt = 0;
        for (int i = i0; i < i1; i++) {
            int g = batch[i];
            if (g != cur) {
                atomicAdd(&gsum[cur * 64 + lane], acc);
                if (lane == 0) atomicAdd(&gcnt[cur], cnt);
                acc = 0.f; cnt = 0; cur = g;
            }
            acc += bf2f(h[(size_t)i * 64 + lane]);
            cnt++;
        }
        atomicAdd(&gsum[cur * 64 + lane], acc);
        if (lane == 0) atomicAdd(&gcnt[cur], cnt);
    }
}

// ---------------- Head, stage 1 ----------------

__global__ __launch_bounds__(TPB) void k_head1(const float* __restrict__ gsum,
                                               const int* __restrict__ gcnt,
                                               const float* __restrict__ fc1w,
                                               const float* __restrict__ fc1b,
                                               float* __restrict__ z) {
    int t = threadIdx.x;
    int g = blockIdx.x * 2 + (t >> 7);
    int o = t & 127;
    int c = gcnt[g]; if (c < 1) c = 1;
    float inv = 1.0f / (float)c;
    float a = fc1b[o];
#pragma unroll 16
    for (int j = 0; j < 64; j++) {
        float pj = gsum[g * 64 + j] * inv;
        a += pj * fc1w[j * 128 + o];
    }
    z[g * 128 + o] = fmaxf(a, 0.f);
}

// ---------------- Head, stage 2 ----------------

__global__ __launch_bounds__(TPB) void k_head2(const float* __restrict__ z,
                                               const float* __restrict__ fc2w,
                                               const float* __restrict__ fc2b,
                                               float* __restrict__ out) {
    int t = threadIdx.x;
    int g = t >> 2, c = t & 3;
    float a = fc2b[c];
#pragma unroll 16
    for (int o = 0; o < 128; o++) a += z[g * 128 + o] * fc2w[o * 4 + c];
    out[t] = a;
}

// ---------------- launch ----------------

extern "C" void kernel_launch(void* const* d_in, const int* in_sizes, int n_in,
                              void* d_out, int out_size, void* d_ws, size_t ws_size,
                              hipStream_t stream) {
    const float* x    = (const float*)d_in[0];
    const int*   ei   = (const int*)d_in[1];
    const int*   batch= (const int*)d_in[2];
    const float* W1   = (const float*)d_in[3];
    const float* b1   = (const float*)d_in[4];
    const float* W2   = (const float*)d_in[5];
    const float* b2   = (const float*)d_in[6];
    const float* fc1w = (const float*)d_in[7];
    const float* fc1b = (const float*)d_in[8];
    const float* fc2w = (const float*)d_in[9];
    const float* fc2b = (const float*)d_in[10];

    const int n = in_sizes[2];        // 50000
    const int E = in_sizes[1] / 2;    // 800000
    const int* srcv = ei;
    const int* dstv = ei + E;
    const int nbuck = (n + 255) >> 8; // 196 (must be <= 256)

    // workspace carve; zeroed region contiguous at front
    char* w = (char*)d_ws;
    int*   gcur   = (int*)w;            w += 256 * 4;
    int*   gcnt   = (int*)w;            w += 64 * 4;
    float* gsum   = (float*)w;          w += 64 * 64 * 4;
    size_t zbytes = (size_t)w - (size_t)d_ws;
    int*   csr_off= (int*)w;            w += (size_t)(n + 1) * 4;
    float* dinv   = (float*)w;          w += (size_t)n * 4;
    int*   csr_src= (int*)w;            w += (size_t)E * 4;
    int*   staged = (int*)w;            w += (size_t)nbuck * BCAP * 4;
    float* zbuf   = (float*)w;          w += 64 * 128 * 4;
    w = (char*)(((size_t)w + 255) & ~(size_t)255);
    bfu* hs = (bfu*)w;                  w += (size_t)n * 64 * 2;
    w = (char*)(((size_t)w + 255) & ~(size_t)255);
    bfu* hb = (bfu*)w;                  w += (size_t)n * 64 * 2;

    hipMemsetAsync(d_ws, 0, zbytes, stream);

    int gA = (E + CHUNK_A - 1) / CHUNK_A;   // 196
    k_passA<<<gA, TPB, 0, stream>>>(srcv, dstv, E, gcur, staged, nbuck);
    k_passB<<<nbuck, TPB, 0, stream>>>(staged, gcur, csr_off, csr_src, dinv, n, nbuck);

    int gRows = (n + 63) / 64;
    int gNode = (n + 3) / 4;
    k_gemm<256, false><<<gRows, TPB, 0, stream>>>(x, W1, dinv, hs, n);
    k_agg<<<gNode, TPB, 0, stream>>>(hs, csr_off, csr_src, dinv, b1, hb, n);
    k_gemm<64, true><<<gRows, TPB, 0, stream>>>(hb, W2, dinv, hs, n);
    k_agg<<<gNode, TPB, 0, stream>>>(hs, csr_off, csr_src, dinv, b2, hb, n);

    int nwaves16 = (n + 15) / 16;
    k_pool<<<(nwaves16 + 3) / 4, TPB, 0, stream>>>(hb, batch, n, gsum, gcnt);
    k_head1<<<32, TPB, 0, stream>>>(gsum, gcnt, fc1w, fc1b, zbuf);
    k_head2<<<1, TPB, 0, stream>>>(zbuf, fc2w, fc2b, (float*)d_out);
}

// Round 10
// 259.232 us; speedup vs baseline: 1.1448x; 1.0456x over previous
//
#include <hip/hip_runtime.h>

// GNN: 2x GCNConv(relu) + mean-pool + MLP head.
// Sizes fixed: N=50000, E=800000, F_IN=256, H=64, NG=64, NC=4.
//
// R9: hs/hb bf16 (halves gather bytes), f32 accumulate. R10: agg gather
// pipeline deepened 8->16/8/4 (R8 counters: 60% latency-wait, VALU 18%,
// HBM 20% -> more outstanding loads per wave, shorter serial tail).

#define TPB 256
#define CHUNK_A 4096
#define BCAP 4608          // per-bucket staging capacity (mean 4096, +8 sigma)

typedef unsigned short bfu;

__device__ __forceinline__ float bf2f(bfu u) {
    union { unsigned u32; float f; } c; c.u32 = ((unsigned)u) << 16; return c.f;
}
__device__ __forceinline__ bfu f2bf(float f) {
    union { float f; unsigned u; } c; c.f = f;
    unsigned r = 0x7FFFu + ((c.u >> 16) & 1u);     // round-to-nearest-even
    return (bfu)((c.u + r) >> 16);
}
__device__ __forceinline__ float blo(unsigned w) {
    union { unsigned u32; float f; } c; c.u32 = w << 16; return c.f;
}
__device__ __forceinline__ float bhi(unsigned w) {
    union { unsigned u32; float f; } c; c.u32 = w & 0xFFFF0000u; return c.f;
}

// ---------------- pass A: chunked bucket staging ----------------
// packed edge: (src<<8) | (dst & 255); requires n <= 65536, nbuck <= 256.

__global__ __launch_bounds__(TPB) void k_passA(const int* __restrict__ srcv,
                                               const int* __restrict__ dstv, int E,
                                               int* __restrict__ gcur,
                                               int* __restrict__ staged, int nbuck) {
    __shared__ int pk[CHUNK_A];
    __shared__ int hist[256];
    __shared__ int ebase[256];
    __shared__ int gbase[256];
    __shared__ int lcur[256];
    int t = threadIdx.x;
    int e0 = blockIdx.x * CHUNK_A;
    int e1 = e0 + CHUNK_A; if (e1 > E) e1 = E;

    hist[t] = 0; lcur[t] = 0;
    __syncthreads();
    for (int i = e0 + t; i < e1; i += TPB) atomicAdd(&hist[dstv[i] >> 8], 1);
    __syncthreads();
    int v = hist[t];
    ebase[t] = v;
    __syncthreads();
    for (int off = 1; off < 256; off <<= 1) {
        int u = (t >= off) ? ebase[t - off] : 0;
        __syncthreads();
        ebase[t] += u;
        __syncthreads();
    }
    ebase[t] -= v;
    if (t < nbuck && v > 0) gbase[t] = t * BCAP + atomicAdd(&gcur[t], v);
    __syncthreads();
    for (int i = e0 + t; i < e1; i += TPB) {
        int d = dstv[i];
        int s = srcv[i];
        int b = d >> 8;
        int r = atomicAdd(&lcur[b], 1);
        pk[ebase[b] + r] = (s << 8) | (d & 255);
    }
    __syncthreads();
    int wave = t >> 6, lane = t & 63;
    for (int b = wave; b < nbuck; b += 4) {
        int c = hist[b];
        int lb = ebase[b];
        int gb = gbase[b];
        for (int j = lane; j < c; j += 64) staged[gb + j] = pk[lb + j];
    }
}

// ---------------- pass B: per-bucket node sort + csr_off + dinv ----------------

__global__ __launch_bounds__(TPB) void k_passB(const int* __restrict__ staged,
                                               const int* __restrict__ gcur,
                                               int* __restrict__ csr_off,
                                               int* __restrict__ csr_src,
                                               float* __restrict__ dinv,
                                               int n, int nbuck) {
    __shared__ int pk[BCAP];
    __shared__ int soff[256];
    __shared__ int hist[256];
    __shared__ int nbase[256];
    __shared__ int cur[256];
    int b = blockIdx.x;
    int n0 = b << 8;
    int n1 = n0 + 256; if (n1 > n) n1 = n;
    int cnt = gcur[b];
    int t = threadIdx.x;

    int cv = (t < nbuck) ? gcur[t] : 0;
    soff[t] = cv;
    hist[t] = 0; cur[t] = 0;
    __syncthreads();
    for (int off = 1; off < 256; off <<= 1) {
        int u = (t >= off) ? soff[t - off] : 0;
        __syncthreads();
        soff[t] += u;
        __syncthreads();
    }
    int base = soff[b] - cnt;   // exclusive prefix at bucket b

    for (int i = t; i < cnt; i += TPB) pk[i] = staged[b * BCAP + i];
    __syncthreads();
    for (int i = t; i < cnt; i += TPB) atomicAdd(&hist[pk[i] & 255], 1);
    __syncthreads();
    int v = hist[t];
    nbase[t] = v;
    __syncthreads();
    for (int off = 1; off < 256; off <<= 1) {
        int u = (t >= off) ? nbase[t - off] : 0;
        __syncthreads();
        nbase[t] += u;
        __syncthreads();
    }
    nbase[t] -= v;
    if (n0 + t < n1) {
        csr_off[n0 + t] = base + nbase[t];
        dinv[n0 + t] = rsqrtf((float)(v + 1));   // +1 self loop
    }
    if (b == nbuck - 1 && t == 0) csr_off[n] = base + cnt;
    __syncthreads();
    for (int i = t; i < cnt; i += TPB) {
        int p = pk[i];
        int dloc = p & 255;
        int r = atomicAdd(&cur[dloc], 1);
        csr_src[base + nbase[dloc] + r] = p >> 8;
    }
}

// ---------------- GEMM: C[r][j] = dinv[r] * sum_k A[r][k] * W[k][j] ----------------

template <int K, bool BF16A>
__global__ __launch_bounds__(TPB) void k_gemm(const void* __restrict__ Av,
                                              const float* __restrict__ W,
                                              const float* __restrict__ dinv,
                                              bfu* __restrict__ C, int n) {
    __shared__ __align__(16) float Wc[64 * 64];
    __shared__ __align__(16) float xr[64 * 68];
    const int t = threadIdx.x;
    const int wave = t >> 6, lane = t & 63;
    const int li = lane >> 4, lj = lane & 15;
    const int rl0 = wave * 16 + li * 4;
    const int rbase = blockIdx.x * 64;

    float acc[4][4] = {{0.f,0.f,0.f,0.f},{0.f,0.f,0.f,0.f},{0.f,0.f,0.f,0.f},{0.f,0.f,0.f,0.f}};

    for (int kc = 0; kc < K; kc += 64) {
        {
            const float4* wsv = (const float4*)(W + (size_t)kc * 64);
            float4* wd = (float4*)Wc;
#pragma unroll
            for (int q = 0; q < 4; q++) wd[t + q * 256] = wsv[t + q * 256];
        }
        {
            int rl = t >> 2;
            int kq = (t & 3) * 16;
            int r = rbase + rl;
            if (!BF16A) {
                const float* A = (const float*)Av;
#pragma unroll
                for (int m = 0; m < 16; m += 4) {
                    float4 xv;
                    if (r < n) xv = *(const float4*)&A[(size_t)r * K + kc + kq + m];
                    else       xv = make_float4(0.f, 0.f, 0.f, 0.f);
                    *(float4*)&xr[rl * 68 + kq + m] = xv;
                }
            } else {
                const bfu* A = (const bfu*)Av;
                uint4 p0 = make_uint4(0,0,0,0), p1 = make_uint4(0,0,0,0);
                if (r < n) {
                    const uint4* ap = (const uint4*)(A + (size_t)r * K + kc + kq);
                    p0 = ap[0]; p1 = ap[1];
                }
                *(float4*)&xr[rl * 68 + kq + 0]  = make_float4(blo(p0.x), bhi(p0.x), blo(p0.y), bhi(p0.y));
                *(float4*)&xr[rl * 68 + kq + 4]  = make_float4(blo(p0.z), bhi(p0.z), blo(p0.w), bhi(p0.w));
                *(float4*)&xr[rl * 68 + kq + 8]  = make_float4(blo(p1.x), bhi(p1.x), blo(p1.y), bhi(p1.y));
                *(float4*)&xr[rl * 68 + kq + 12] = make_float4(blo(p1.z), bhi(p1.z), blo(p1.w), bhi(p1.w));
            }
        }
        __syncthreads();
#pragma unroll 8
        for (int kk = 0; kk < 64; kk++) {
            float4 wv = *(const float4*)&Wc[kk * 64 + lj * 4];
            float x0 = xr[(rl0 + 0) * 68 + kk];
            float x1 = xr[(rl0 + 1) * 68 + kk];
            float x2 = xr[(rl0 + 2) * 68 + kk];
            float x3 = xr[(rl0 + 3) * 68 + kk];
            acc[0][0] += x0 * wv.x; acc[0][1] += x0 * wv.y; acc[0][2] += x0 * wv.z; acc[0][3] += x0 * wv.w;
            acc[1][0] += x1 * wv.x; acc[1][1] += x1 * wv.y; acc[1][2] += x1 * wv.z; acc[1][3] += x1 * wv.w;
            acc[2][0] += x2 * wv.x; acc[2][1] += x2 * wv.y; acc[2][2] += x2 * wv.z; acc[2][3] += x2 * wv.w;
            acc[3][0] += x3 * wv.x; acc[3][1] += x3 * wv.y; acc[3][2] += x3 * wv.z; acc[3][3] += x3 * wv.w;
        }
        __syncthreads();
    }

#pragma unroll
    for (int ri = 0; ri < 4; ri++) {
        int r = rbase + rl0 + ri;
        if (r < n) {
            float d = dinv[r];
            ushort4 o;
            o.x = f2bf(acc[ri][0] * d);
            o.y = f2bf(acc[ri][1] * d);
            o.z = f2bf(acc[ri][2] * d);
            o.w = f2bf(acc[ri][3] * d);
            *(ushort4*)&C[(size_t)r * 64 + lj * 4] = o;
        }
    }
}

// ---------------- Aggregation (CSR gather, bf16 rows, deep pipeline) ----------------

__global__ __launch_bounds__(TPB) void k_agg(const bfu* __restrict__ hs,
                                             const int* __restrict__ csr_off,
                                             const int* __restrict__ csr_src,
                                             const float* __restrict__ dinv,
                                             const float* __restrict__ bias,
                                             bfu* __restrict__ out, int n) {
    int node = blockIdx.x * 4 + (threadIdx.x >> 6);
    int lane = threadIdx.x & 63;
    if (node >= n) return;
    int p0 = csr_off[node];
    int p1 = csr_off[node + 1];
    float acc = bf2f(hs[(size_t)node * 64 + lane]);  // self loop
    int p = p0;
    // 16-wide batches: 16 index loads then 16 gathers, all in flight
    for (; p + 16 <= p1; p += 16) {
        int s[16];
#pragma unroll
        for (int i = 0; i < 16; i++) s[i] = csr_src[p + i];
        float a[16];
#pragma unroll
        for (int i = 0; i < 16; i++) a[i] = bf2f(hs[(size_t)s[i] * 64 + lane]);
        float t0 = ((a[0] + a[1]) + (a[2] + a[3])) + ((a[4] + a[5]) + (a[6] + a[7]));
        float t1 = ((a[8] + a[9]) + (a[10] + a[11])) + ((a[12] + a[13]) + (a[14] + a[15]));
        acc += t0 + t1;
    }
    if (p + 8 <= p1) {
        int s[8];
#pragma unroll
        for (int i = 0; i < 8; i++) s[i] = csr_src[p + i];
        float a[8];
#pragma unroll
        for (int i = 0; i < 8; i++) a[i] = bf2f(hs[(size_t)s[i] * 64 + lane]);
        acc += ((a[0] + a[1]) + (a[2] + a[3])) + ((a[4] + a[5]) + (a[6] + a[7]));
        p += 8;
    }
    if (p + 4 <= p1) {
        int s[4];
#pragma unroll
        for (int i = 0; i < 4; i++) s[i] = csr_src[p + i];
        float a[4];
#pragma unroll
        for (int i = 0; i < 4; i++) a[i] = bf2f(hs[(size_t)s[i] * 64 + lane]);
        acc += (a[0] + a[1]) + (a[2] + a[3]);
        p += 4;
    }
    for (; p < p1; p++) acc += bf2f(hs[(size_t)csr_src[p] * 64 + lane]);
    float v = dinv[node] * acc + bias[lane];
    out[(size_t)node * 64 + lane] = f2bf(fmaxf(v, 0.f));
}

// ---------------- Pool: sorted batch; uniform-chunk fast path (bf16 reads) ----------------

__global__ __launch_bounds__(TPB) void k_pool(const bfu* __restrict__ h,
                                              const int* __restrict__ batch, int n,
                                              float* __restrict__ gsum,
                                              int* __restrict__ gcnt) {
    const int CH = 16;
    int wid = blockIdx.x * 4 + (threadIdx.x >> 6);
    int lane = threadIdx.x & 63;
    int i0 = wid * CH;
    if (i0 >= n) return;
    int i1 = i0 + CH; if (i1 > n) i1 = n;
    int g0 = batch[i0];
    int g1 = batch[i1 - 1];
    if (g0 == g1) {
        float acc = 0.f;
#pragma unroll
        for (int i = 0; i < CH; i++) {
            int idx = i0 + i;
            if (idx < i1) acc += bf2f(h[(size_t)idx * 64 + lane]);
        }
        atomicAdd(&gsum[g0 * 64 + lane], acc);
        if (lane == 0) atomicAdd(&gcnt[g0], i1 - i0);
    } else {
        int cur = g0;
        float acc = 0.f;
        int cnt = 0;
        for (int i = i0; i < i1; i++) {
            int g = batch[i];
            if (g != cur) {
                atomicAdd(&gsum[cur * 64 + lane], acc);
                if (lane == 0) atomicAdd(&gcnt[cur], cnt);
                acc = 0.f; cnt = 0; cur = g;
            }
            acc += bf2f(h[(size_t)i * 64 + lane]);
            cnt++;
        }
        atomicAdd(&gsum[cur * 64 + lane], acc);
        if (lane == 0) atomicAdd(&gcnt[cur], cnt);
    }
}

// ---------------- Head, stage 1 ----------------

__global__ __launch_bounds__(TPB) void k_head1(const float* __restrict__ gsum,
                                               const int* __restrict__ gcnt,
                                               const float* __restrict__ fc1w,
                                               const float* __restrict__ fc1b,
                                               float* __restrict__ z) {
    int t = threadIdx.x;
    int g = blockIdx.x * 2 + (t >> 7);
    int o = t & 127;
    int c = gcnt[g]; if (c < 1) c = 1;
    float inv = 1.0f / (float)c;
    float a = fc1b[o];
#pragma unroll 16
    for (int j = 0; j < 64; j++) {
        float pj = gsum[g * 64 + j] * inv;
        a += pj * fc1w[j * 128 + o];
    }
    z[g * 128 + o] = fmaxf(a, 0.f);
}

// ---------------- Head, stage 2 ----------------

__global__ __launch_bounds__(TPB) void k_head2(const float* __restrict__ z,
                                               const float* __restrict__ fc2w,
                                               const float* __restrict__ fc2b,
                                               float* __restrict__ out) {
    int t = threadIdx.x;
    int g = t >> 2, c = t & 3;
    float a = fc2b[c];
#pragma unroll 16
    for (int o = 0; o < 128; o++) a += z[g * 128 + o] * fc2w[o * 4 + c];
    out[t] = a;
}

// ---------------- launch ----------------

extern "C" void kernel_launch(void* const* d_in, const int* in_sizes, int n_in,
                              void* d_out, int out_size, void* d_ws, size_t ws_size,
                              hipStream_t stream) {
    const float* x    = (const float*)d_in[0];
    const int*   ei   = (const int*)d_in[1];
    const int*   batch= (const int*)d_in[2];
    const float* W1   = (const float*)d_in[3];
    const float* b1   = (const float*)d_in[4];
    const float* W2   = (const float*)d_in[5];
    const float* b2   = (const float*)d_in[6];
    const float* fc1w = (const float*)d_in[7];
    const float* fc1b = (const float*)d_in[8];
    const float* fc2w = (const float*)d_in[9];
    const float* fc2b = (const float*)d_in[10];

    const int n = in_sizes[2];        // 50000
    const int E = in_sizes[1] / 2;    // 800000
    const int* srcv = ei;
    const int* dstv = ei + E;
    const int nbuck = (n + 255) >> 8; // 196 (must be <= 256)

    // workspace carve; zeroed region contiguous at front
    char* w = (char*)d_ws;
    int*   gcur   = (int*)w;            w += 256 * 4;
    int*   gcnt   = (int*)w;            w += 64 * 4;
    float* gsum   = (float*)w;          w += 64 * 64 * 4;
    size_t zbytes = (size_t)w - (size_t)d_ws;
    int*   csr_off= (int*)w;            w += (size_t)(n + 1) * 4;
    float* dinv   = (float*)w;          w += (size_t)n * 4;
    int*   csr_src= (int*)w;            w += (size_t)E * 4;
    int*   staged = (int*)w;            w += (size_t)nbuck * BCAP * 4;
    float* zbuf   = (float*)w;          w += 64 * 128 * 4;
    w = (char*)(((size_t)w + 255) & ~(size_t)255);
    bfu* hs = (bfu*)w;                  w += (size_t)n * 64 * 2;
    w = (char*)(((size_t)w + 255) & ~(size_t)255);
    bfu* hb = (bfu*)w;                  w += (size_t)n * 64 * 2;

    hipMemsetAsync(d_ws, 0, zbytes, stream);

    int gA = (E + CHUNK_A - 1) / CHUNK_A;   // 196
    k_passA<<<gA, TPB, 0, stream>>>(srcv, dstv, E, gcur, staged, nbuck);
    k_passB<<<nbuck, TPB, 0, stream>>>(staged, gcur, csr_off, csr_src, dinv, n, nbuck);

    int gRows = (n + 63) / 64;
    int gNode = (n + 3) / 4;
    k_gemm<256, false><<<gRows, TPB, 0, stream>>>(x, W1, dinv, hs, n);
    k_agg<<<gNode, TPB, 0, stream>>>(hs, csr_off, csr_src, dinv, b1, hb, n);
    k_gemm<64, true><<<gRows, TPB, 0, stream>>>(hb, W2, dinv, hs, n);
    k_agg<<<gNode, TPB, 0, stream>>>(hs, csr_off, csr_src, dinv, b2, hb, n);

    int nwaves16 = (n + 15) / 16;
    k_pool<<<(nwaves16 + 3) / 4, TPB, 0, stream>>>(hb, batch, n, gsum, gcnt);
    k_head1<<<32, TPB, 0, stream>>>(gsum, gcnt, fc1w, fc1b, zbuf);
    k_head2<<<1, TPB, 0, stream>>>(zbuf, fc2w, fc2b, (float*)d_out);
}

// Round 11
// 250.767 us; speedup vs baseline: 1.1835x; 1.0338x over previous
//
#include <hip/hip_runtime.h>

// GNN: 2x GCNConv(relu) + mean-pool + MLP head.
// Sizes fixed: N=50000, E=800000, F_IN=256, H=64, NG=64, NC=4.
//
// R9: hs/hb bf16 (halves gather bytes), f32 accumulate.
// R10: deep gather pipeline (16/8/4).
// R11: dual-edge packed gather — wave splits into 2 halves, lane loads uint
// (2 bf16 features), one VMEM instruction covers 2 edges (256B vs 128B);
// halves combined via shfl_xor(32).

#define TPB 256
#define CHUNK_A 4096
#define BCAP 4608          // per-bucket staging capacity (mean 4096, +8 sigma)

typedef unsigned short bfu;

__device__ __forceinline__ float bf2f(bfu u) {
    union { unsigned u32; float f; } c; c.u32 = ((unsigned)u) << 16; return c.f;
}
__device__ __forceinline__ bfu f2bf(float f) {
    union { float f; unsigned u; } c; c.f = f;
    unsigned r = 0x7FFFu + ((c.u >> 16) & 1u);     // round-to-nearest-even
    return (bfu)((c.u + r) >> 16);
}
__device__ __forceinline__ float blo(unsigned w) {
    union { unsigned u32; float f; } c; c.u32 = w << 16; return c.f;
}
__device__ __forceinline__ float bhi(unsigned w) {
    union { unsigned u32; float f; } c; c.u32 = w & 0xFFFF0000u; return c.f;
}

// ---------------- pass A: chunked bucket staging ----------------
// packed edge: (src<<8) | (dst & 255); requires n <= 65536, nbuck <= 256.

__global__ __launch_bounds__(TPB) void k_passA(const int* __restrict__ srcv,
                                               const int* __restrict__ dstv, int E,
                                               int* __restrict__ gcur,
                                               int* __restrict__ staged, int nbuck) {
    __shared__ int pk[CHUNK_A];
    __shared__ int hist[256];
    __shared__ int ebase[256];
    __shared__ int gbase[256];
    __shared__ int lcur[256];
    int t = threadIdx.x;
    int e0 = blockIdx.x * CHUNK_A;
    int e1 = e0 + CHUNK_A; if (e1 > E) e1 = E;

    hist[t] = 0; lcur[t] = 0;
    __syncthreads();
    for (int i = e0 + t; i < e1; i += TPB) atomicAdd(&hist[dstv[i] >> 8], 1);
    __syncthreads();
    int v = hist[t];
    ebase[t] = v;
    __syncthreads();
    for (int off = 1; off < 256; off <<= 1) {
        int u = (t >= off) ? ebase[t - off] : 0;
        __syncthreads();
        ebase[t] += u;
        __syncthreads();
    }
    ebase[t] -= v;
    if (t < nbuck && v > 0) gbase[t] = t * BCAP + atomicAdd(&gcur[t], v);
    __syncthreads();
    for (int i = e0 + t; i < e1; i += TPB) {
        int d = dstv[i];
        int s = srcv[i];
        int b = d >> 8;
        int r = atomicAdd(&lcur[b], 1);
        pk[ebase[b] + r] = (s << 8) | (d & 255);
    }
    __syncthreads();
    int wave = t >> 6, lane = t & 63;
    for (int b = wave; b < nbuck; b += 4) {
        int c = hist[b];
        int lb = ebase[b];
        int gb = gbase[b];
        for (int j = lane; j < c; j += 64) staged[gb + j] = pk[lb + j];
    }
}

// ---------------- pass B: per-bucket node sort + csr_off + dinv ----------------

__global__ __launch_bounds__(TPB) void k_passB(const int* __restrict__ staged,
                                               const int* __restrict__ gcur,
                                               int* __restrict__ csr_off,
                                               int* __restrict__ csr_src,
                                               float* __restrict__ dinv,
                                               int n, int nbuck) {
    __shared__ int pk[BCAP];
    __shared__ int soff[256];
    __shared__ int hist[256];
    __shared__ int nbase[256];
    __shared__ int cur[256];
    int b = blockIdx.x;
    int n0 = b << 8;
    int n1 = n0 + 256; if (n1 > n) n1 = n;
    int cnt = gcur[b];
    int t = threadIdx.x;

    int cv = (t < nbuck) ? gcur[t] : 0;
    soff[t] = cv;
    hist[t] = 0; cur[t] = 0;
    __syncthreads();
    for (int off = 1; off < 256; off <<= 1) {
        int u = (t >= off) ? soff[t - off] : 0;
        __syncthreads();
        soff[t] += u;
        __syncthreads();
    }
    int base = soff[b] - cnt;   // exclusive prefix at bucket b

    for (int i = t; i < cnt; i += TPB) pk[i] = staged[b * BCAP + i];
    __syncthreads();
    for (int i = t; i < cnt; i += TPB) atomicAdd(&hist[pk[i] & 255], 1);
    __syncthreads();
    int v = hist[t];
    nbase[t] = v;
    __syncthreads();
    for (int off = 1; off < 256; off <<= 1) {
        int u = (t >= off) ? nbase[t - off] : 0;
        __syncthreads();
        nbase[t] += u;
        __syncthreads();
    }
    nbase[t] -= v;
    if (n0 + t < n1) {
        csr_off[n0 + t] = base + nbase[t];
        dinv[n0 + t] = rsqrtf((float)(v + 1));   // +1 self loop
    }
    if (b == nbuck - 1 && t == 0) csr_off[n] = base + cnt;
    __syncthreads();
    for (int i = t; i < cnt; i += TPB) {
        int p = pk[i];
        int dloc = p & 255;
        int r = atomicAdd(&cur[dloc], 1);
        csr_src[base + nbase[dloc] + r] = p >> 8;
    }
}

// ---------------- GEMM: C[r][j] = dinv[r] * sum_k A[r][k] * W[k][j] ----------------

template <int K, bool BF16A>
__global__ __launch_bounds__(TPB) void k_gemm(const void* __restrict__ Av,
                                              const float* __restrict__ W,
                                              const float* __restrict__ dinv,
                                              bfu* __restrict__ C, int n) {
    __shared__ __align__(16) float Wc[64 * 64];
    __shared__ __align__(16) float xr[64 * 68];
    const int t = threadIdx.x;
    const int wave = t >> 6, lane = t & 63;
    const int li = lane >> 4, lj = lane & 15;
    const int rl0 = wave * 16 + li * 4;
    const int rbase = blockIdx.x * 64;

    float acc[4][4] = {{0.f,0.f,0.f,0.f},{0.f,0.f,0.f,0.f},{0.f,0.f,0.f,0.f},{0.f,0.f,0.f,0.f}};

    for (int kc = 0; kc < K; kc += 64) {
        {
            const float4* wsv = (const float4*)(W + (size_t)kc * 64);
            float4* wd = (float4*)Wc;
#pragma unroll
            for (int q = 0; q < 4; q++) wd[t + q * 256] = wsv[t + q * 256];
        }
        {
            int rl = t >> 2;
            int kq = (t & 3) * 16;
            int r = rbase + rl;
            if (!BF16A) {
                const float* A = (const float*)Av;
#pragma unroll
                for (int m = 0; m < 16; m += 4) {
                    float4 xv;
                    if (r < n) xv = *(const float4*)&A[(size_t)r * K + kc + kq + m];
                    else       xv = make_float4(0.f, 0.f, 0.f, 0.f);
                    *(float4*)&xr[rl * 68 + kq + m] = xv;
                }
            } else {
                const bfu* A = (const bfu*)Av;
                uint4 p0 = make_uint4(0,0,0,0), p1 = make_uint4(0,0,0,0);
                if (r < n) {
                    const uint4* ap = (const uint4*)(A + (size_t)r * K + kc + kq);
                    p0 = ap[0]; p1 = ap[1];
                }
                *(float4*)&xr[rl * 68 + kq + 0]  = make_float4(blo(p0.x), bhi(p0.x), blo(p0.y), bhi(p0.y));
                *(float4*)&xr[rl * 68 + kq + 4]  = make_float4(blo(p0.z), bhi(p0.z), blo(p0.w), bhi(p0.w));
                *(float4*)&xr[rl * 68 + kq + 8]  = make_float4(blo(p1.x), bhi(p1.x), blo(p1.y), bhi(p1.y));
                *(float4*)&xr[rl * 68 + kq + 12] = make_float4(blo(p1.z), bhi(p1.z), blo(p1.w), bhi(p1.w));
            }
        }
        __syncthreads();
#pragma unroll 8
        for (int kk = 0; kk < 64; kk++) {
            float4 wv = *(const float4*)&Wc[kk * 64 + lj * 4];
            float x0 = xr[(rl0 + 0) * 68 + kk];
            float x1 = xr[(rl0 + 1) * 68 + kk];
            float x2 = xr[(rl0 + 2) * 68 + kk];
            float x3 = xr[(rl0 + 3) * 68 + kk];
            acc[0][0] += x0 * wv.x; acc[0][1] += x0 * wv.y; acc[0][2] += x0 * wv.z; acc[0][3] += x0 * wv.w;
            acc[1][0] += x1 * wv.x; acc[1][1] += x1 * wv.y; acc[1][2] += x1 * wv.z; acc[1][3] += x1 * wv.w;
            acc[2][0] += x2 * wv.x; acc[2][1] += x2 * wv.y; acc[2][2] += x2 * wv.z; acc[2][3] += x2 * wv.w;
            acc[3][0] += x3 * wv.x; acc[3][1] += x3 * wv.y; acc[3][2] += x3 * wv.z; acc[3][3] += x3 * wv.w;
        }
        __syncthreads();
    }

#pragma unroll
    for (int ri = 0; ri < 4; ri++) {
        int r = rbase + rl0 + ri;
        if (r < n) {
            float d = dinv[r];
            ushort4 o;
            o.x = f2bf(acc[ri][0] * d);
            o.y = f2bf(acc[ri][1] * d);
            o.z = f2bf(acc[ri][2] * d);
            o.w = f2bf(acc[ri][3] * d);
            *(ushort4*)&C[(size_t)r * 64 + lj * 4] = o;
        }
    }
}

// ---------------- Aggregation: dual-edge packed gather ----------------
// Wave = 2 halves of 32 lanes; lane handles 2 features (uint = 2 bf16).
// One gather instruction covers 2 edges (256B). Halves combined by shfl_xor.

__global__ __launch_bounds__(TPB) void k_agg(const bfu* __restrict__ hs,
                                             const int* __restrict__ csr_off,
                                             const int* __restrict__ csr_src,
                                             const float* __restrict__ dinv,
                                             const float* __restrict__ bias,
                                             bfu* __restrict__ out, int n) {
    int node = blockIdx.x * 4 + (threadIdx.x >> 6);
    int lane = threadIdx.x & 63;
    int half = lane >> 5;          // 0 or 1
    int fl = (lane & 31) * 2;      // feature pair base
    if (node >= n) return;
    int p0 = csr_off[node];
    int p1 = csr_off[node + 1];

    float ax = 0.f, ay = 0.f;
    {   // self loop: half 0 only
        unsigned g = *(const unsigned*)(hs + (size_t)node * 64 + fl);
        if (half == 0) { ax = blo(g); ay = bhi(g); }
    }
    int p = p0;
    // 8 edge-pairs = 16 edges in flight
    for (; p + 16 <= p1; p += 16) {
        int s[8]; unsigned g[8];
#pragma unroll
        for (int i = 0; i < 8; i++) s[i] = csr_src[p + 2 * i + half];
#pragma unroll
        for (int i = 0; i < 8; i++) g[i] = *(const unsigned*)(hs + (size_t)s[i] * 64 + fl);
#pragma unroll
        for (int i = 0; i < 8; i++) { ax += blo(g[i]); ay += bhi(g[i]); }
    }
    if (p + 8 <= p1) {
        int s[4]; unsigned g[4];
#pragma unroll
        for (int i = 0; i < 4; i++) s[i] = csr_src[p + 2 * i + half];
#pragma unroll
        for (int i = 0; i < 4; i++) g[i] = *(const unsigned*)(hs + (size_t)s[i] * 64 + fl);
#pragma unroll
        for (int i = 0; i < 4; i++) { ax += blo(g[i]); ay += bhi(g[i]); }
        p += 8;
    }
    if (p + 4 <= p1) {
        int s[2]; unsigned g[2];
#pragma unroll
        for (int i = 0; i < 2; i++) s[i] = csr_src[p + 2 * i + half];
#pragma unroll
        for (int i = 0; i < 2; i++) g[i] = *(const unsigned*)(hs + (size_t)s[i] * 64 + fl);
#pragma unroll
        for (int i = 0; i < 2; i++) { ax += blo(g[i]); ay += bhi(g[i]); }
        p += 4;
    }
    if (p + 2 <= p1) {
        int s = csr_src[p + half];
        unsigned g = *(const unsigned*)(hs + (size_t)s * 64 + fl);
        ax += blo(g); ay += bhi(g);
        p += 2;
    }
    if (p < p1) {   // odd tail: half 0 only
        int s = csr_src[p];
        unsigned g = *(const unsigned*)(hs + (size_t)s * 64 + fl);
        if (half == 0) { ax += blo(g); ay += bhi(g); }
    }
    // combine halves (same fl in lane and lane^32)
    ax += __shfl_xor(ax, 32);
    ay += __shfl_xor(ay, 32);

    float d = dinv[node];
    float vx = fmaxf(d * ax + bias[fl + 0], 0.f);
    float vy = fmaxf(d * ay + bias[fl + 1], 0.f);
    if (half == 0) {
        ushort2 o;
        o.x = f2bf(vx);
        o.y = f2bf(vy);
        *(ushort2*)(out + (size_t)node * 64 + fl) = o;
    }
}

// ---------------- Pool: sorted batch; uniform-chunk fast path (bf16 reads) ----------------

__global__ __launch_bounds__(TPB) void k_pool(const bfu* __restrict__ h,
                                              const int* __restrict__ batch, int n,
                                              float* __restrict__ gsum,
                                              int* __restrict__ gcnt) {
    const int CH = 16;
    int wid = blockIdx.x * 4 + (threadIdx.x >> 6);
    int lane = threadIdx.x & 63;
    int i0 = wid * CH;
    if (i0 >= n) return;
    int i1 = i0 + CH; if (i1 > n) i1 = n;
    int g0 = batch[i0];
    int g1 = batch[i1 - 1];
    if (g0 == g1) {
        float acc = 0.f;
#pragma unroll
        for (int i = 0; i < CH; i++) {
            int idx = i0 + i;
            if (idx < i1) acc += bf2f(h[(size_t)idx * 64 + lane]);
        }
        atomicAdd(&gsum[g0 * 64 + lane], acc);
        if (lane == 0) atomicAdd(&gcnt[g0], i1 - i0);
    } else {
        int cur = g0;
        float acc = 0.f;
        int cnt = 0;
        for (int i = i0; i < i1; i++) {
            int g = batch[i];
            if (g != cur) {
                atomicAdd(&gsum[cur * 64 + lane], acc);
                if (lane == 0) atomicAdd(&gcnt[cur], cnt);
                acc = 0.f; cnt = 0; cur = g;
            }
            acc += bf2f(h[(size_t)i * 64 + lane]);
            cnt++;
        }
        atomicAdd(&gsum[cur * 64 + lane], acc);
        if (lane == 0) atomicAdd(&gcnt[cur], cnt);
    }
}

// ---------------- Head, stage 1 ----------------

__global__ __launch_bounds__(TPB) void k_head1(const float* __restrict__ gsum,
                                               const int* __restrict__ gcnt,
                                               const float* __restrict__ fc1w,
                                               const float* __restrict__ fc1b,
                                               float* __restrict__ z) {
    int t = threadIdx.x;
    int g = blockIdx.x * 2 + (t >> 7);
    int o = t & 127;
    int c = gcnt[g]; if (c < 1) c = 1;
    float inv = 1.0f / (float)c;
    float a = fc1b[o];
#pragma unroll 16
    for (int j = 0; j < 64; j++) {
        float pj = gsum[g * 64 + j] * inv;
        a += pj * fc1w[j * 128 + o];
    }
    z[g * 128 + o] = fmaxf(a, 0.f);
}

// ---------------- Head, stage 2 ----------------

__global__ __launch_bounds__(TPB) void k_head2(const float* __restrict__ z,
                                               const float* __restrict__ fc2w,
                                               const float* __restrict__ fc2b,
                                               float* __restrict__ out) {
    int t = threadIdx.x;
    int g = t >> 2, c = t & 3;
    float a = fc2b[c];
#pragma unroll 16
    for (int o = 0; o < 128; o++) a += z[g * 128 + o] * fc2w[o * 4 + c];
    out[t] = a;
}

// ---------------- launch ----------------

extern "C" void kernel_launch(void* const* d_in, const int* in_sizes, int n_in,
                              void* d_out, int out_size, void* d_ws, size_t ws_size,
                              hipStream_t stream) {
    const float* x    = (const float*)d_in[0];
    const int*   ei   = (const int*)d_in[1];
    const int*   batch= (const int*)d_in[2];
    const float* W1   = (const float*)d_in[3];
    const float* b1   = (const float*)d_in[4];
    const float* W2   = (const float*)d_in[5];
    const float* b2   = (const float*)d_in[6];
    const float* fc1w = (const float*)d_in[7];
    const float* fc1b = (const float*)d_in[8];
    const float* fc2w = (const float*)d_in[9];
    const float* fc2b = (const float*)d_in[10];

    const int n = in_sizes[2];        // 50000
    const int E = in_sizes[1] / 2;    // 800000
    const int* srcv = ei;
    const int* dstv = ei + E;
    const int nbuck = (n + 255) >> 8; // 196 (must be <= 256)

    // workspace carve; zeroed region contiguous at front
    char* w = (char*)d_ws;
    int*   gcur   = (int*)w;            w += 256 * 4;
    int*   gcnt   = (int*)w;            w += 64 * 4;
    float* gsum   = (float*)w;          w += 64 * 64 * 4;
    size_t zbytes = (size_t)w - (size_t)d_ws;
    int*   csr_off= (int*)w;            w += (size_t)(n + 1) * 4;
    float* dinv   = (float*)w;          w += (size_t)n * 4;
    int*   csr_src= (int*)w;            w += (size_t)E * 4;
    int*   staged = (int*)w;            w += (size_t)nbuck * BCAP * 4;
    float* zbuf   = (float*)w;          w += 64 * 128 * 4;
    w = (char*)(((size_t)w + 255) & ~(size_t)255);
    bfu* hs = (bfu*)w;                  w += (size_t)n * 64 * 2;
    w = (char*)(((size_t)w + 255) & ~(size_t)255);
    bfu* hb = (bfu*)w;                  w += (size_t)n * 64 * 2;

    hipMemsetAsync(d_ws, 0, zbytes, stream);

    int gA = (E + CHUNK_A - 1) / CHUNK_A;   // 196
    k_passA<<<gA, TPB, 0, stream>>>(srcv, dstv, E, gcur, staged, nbuck);
    k_passB<<<nbuck, TPB, 0, stream>>>(staged, gcur, csr_off, csr_src, dinv, n, nbuck);

    int gRows = (n + 63) / 64;
    int gNode = (n + 3) / 4;
    k_gemm<256, false><<<gRows, TPB, 0, stream>>>(x, W1, dinv, hs, n);
    k_agg<<<gNode, TPB, 0, stream>>>(hs, csr_off, csr_src, dinv, b1, hb, n);
    k_gemm<64, true><<<gRows, TPB, 0, stream>>>(hb, W2, dinv, hs, n);
    k_agg<<<gNode, TPB, 0, stream>>>(hs, csr_off, csr_src, dinv, b2, hb, n);

    int nwaves16 = (n + 15) / 16;
    k_pool<<<(nwaves16 + 3) / 4, TPB, 0, stream>>>(hb, batch, n, gsum, gcnt);
    k_head1<<<32, TPB, 0, stream>>>(gsum, gcnt, fc1w, fc1b, zbuf);
    k_head2<<<1, TPB, 0, stream>>>(zbuf, fc2w, fc2b, (float*)d_out);
}